// Round 1
// baseline (539.784 us; speedup 1.0000x reference)
//
#include <hip/hip_runtime.h>
#include <hip/hip_bf16.h>

typedef short s16x8 __attribute__((ext_vector_type(8)));
typedef float f32x4 __attribute__((ext_vector_type(4)));

#define MFMA_BF16(a,b,c) __builtin_amdgcn_mfma_f32_16x16x32_bf16((a),(b),(c),0,0,0)

static __device__ __forceinline__ unsigned short f2bf(float f){
  unsigned u = __builtin_bit_cast(unsigned, f);
  u += 0x7fffu + ((u >> 16) & 1u);          // RNE
  return (unsigned short)(u >> 16);
}
static __device__ __forceinline__ float bf2f(unsigned short h){
  unsigned u = ((unsigned)h) << 16;
  return __builtin_bit_cast(float, u);
}
// XOR swizzle: flip low 3 bits of the 16B-chunk index with (row&7)
static __device__ __forceinline__ int swz128(int row, int col){
  return row*128 + ((col & 7) | (((col >> 3) ^ (row & 7)) << 3));
}
static __device__ __forceinline__ int swz64(int row, int col){
  return row*64 + ((col & 7) | (((col >> 3) ^ (row & 7)) << 3));
}
static __device__ __forceinline__ int swz512(int row, int col){
  return row*512 + ((col & 7) | (((col >> 3) ^ (row & 7)) << 3));
}

// ---------------- kernel 0: W transpose + hi/lo split, pre-swizzled ----------
__global__ __launch_bounds__(256) void k0_wt(const float* __restrict__ W,
                                             unsigned short* __restrict__ wtH,
                                             unsigned short* __restrict__ wtL){
  __shared__ float tile[32][257];
  const int t = threadIdx.x;                 // 256 threads, t = output col n
  for (int cc = 0; cc < 128; cc += 32){
    #pragma unroll
    for (int k = 0; k < 32; ++k)
      tile[k][t] = W[(size_t)(cc + k)*256 + t];   // coalesced
    __syncthreads();
    #pragma unroll
    for (int k = 0; k < 32; ++k){
      const float v = tile[k][t];
      const int c = cc + k;
      const unsigned short h = f2bf(v);
      const unsigned short l = f2bf(v - bf2f(h));
      const int cs = (c & 7) | (((c >> 3) ^ (t & 7)) << 3); // pre-swizzle
      wtH[t*128 + cs] = h;
      wtL[t*128 + cs] = l;
    }
    __syncthreads();
  }
}

// ---------------- kernel 1: qkv = x @ W (split-bf16, fp32-exact-ish) --------
// writes q,k fp32 -> qk[row][0..127]; v bf16 transposed -> vT[head][ch][pos]
__global__ __launch_bounds__(512,2) void k1_qkv(const float* __restrict__ x,
    const unsigned short* __restrict__ wtH, const unsigned short* __restrict__ wtL,
    float* __restrict__ qk, unsigned short* __restrict__ vT){
  __shared__ unsigned short xh[16384], xl[16384], wth[16384], wtl[16384]; // 128 KB
  const int t = threadIdx.x;
  const int lane = t & 63, wid = t >> 6;
  const int li = lane & 15, g = lane >> 4;
  const int m0 = blockIdx.x * 128;
  const int wm = wid >> 2, wn = wid & 3;

  // stage x tile (128 rows x 128 ch), split hi/lo, swizzled
  {
    const int row = t >> 2, cb = (t & 3) * 32;
    const float* src = x + (size_t)(m0 + row)*128 + cb;
    #pragma unroll
    for (int gg = 0; gg < 4; ++gg){
      const float4 v0 = ((const float4*)src)[2*gg];
      const float4 v1 = ((const float4*)src)[2*gg + 1];
      const float vv[8] = {v0.x,v0.y,v0.z,v0.w,v1.x,v1.y,v1.z,v1.w};
      s16x8 h, l;
      #pragma unroll
      for (int j = 0; j < 8; ++j){
        const unsigned short hb = f2bf(vv[j]);
        h[j] = (short)hb;
        l[j] = (short)f2bf(vv[j] - bf2f(hb));
      }
      const int idx = swz128(row, cb + 8*gg);
      *(s16x8*)&xh[idx] = h;
      *(s16x8*)&xl[idx] = l;
    }
  }

  for (int nh = 0; nh < 2; ++nh){
    if (nh) __syncthreads();                 // protect wt reuse
    {                                        // stage WT half (pre-swizzled, linear copy)
      const s16x8* sh = (const s16x8*)(wtH + nh*16384);
      const s16x8* sl = (const s16x8*)(wtL + nh*16384);
      #pragma unroll
      for (int i2 = 0; i2 < 4; ++i2){
        ((s16x8*)wth)[t + i2*512] = sh[t + i2*512];
        ((s16x8*)wtl)[t + i2*512] = sl[t + i2*512];
      }
    }
    __syncthreads();

    f32x4 acc[4][2] = {};
    #pragma unroll
    for (int ks = 0; ks < 4; ++ks){
      const int col = ks*32 + g*8;
      s16x8 ah[4], al[4], bh[2], bl[2];
      #pragma unroll
      for (int mi = 0; mi < 4; ++mi){
        const int idx = swz128(wm*64 + mi*16 + li, col);
        ah[mi] = *(const s16x8*)&xh[idx];
        al[mi] = *(const s16x8*)&xl[idx];
      }
      #pragma unroll
      for (int ni = 0; ni < 2; ++ni){
        const int idx = swz128(wn*32 + ni*16 + li, col);
        bh[ni] = *(const s16x8*)&wth[idx];
        bl[ni] = *(const s16x8*)&wtl[idx];
      }
      #pragma unroll
      for (int mi = 0; mi < 4; ++mi)
        #pragma unroll
        for (int ni = 0; ni < 2; ++ni){
          acc[mi][ni] = MFMA_BF16(ah[mi], bh[ni], acc[mi][ni]);
          acc[mi][ni] = MFMA_BF16(ah[mi], bl[ni], acc[mi][ni]);
          acc[mi][ni] = MFMA_BF16(al[mi], bh[ni], acc[mi][ni]);
        }
    }

    if (nh == 0){
      #pragma unroll
      for (int mi = 0; mi < 4; ++mi)
        #pragma unroll
        for (int ni = 0; ni < 2; ++ni)
          #pragma unroll
          for (int r = 0; r < 4; ++r){
            const int grow = m0 + wm*64 + mi*16 + g*4 + r;
            const int coln = wn*32 + ni*16 + li;
            qk[(size_t)grow*128 + coln] = acc[mi][ni][r];
          }
    } else {
      #pragma unroll
      for (int mi = 0; mi < 4; ++mi)
        #pragma unroll
        for (int ni = 0; ni < 2; ++ni)
          #pragma unroll
          for (int r = 0; r < 4; ++r){
            const int grow = m0 + wm*64 + mi*16 + g*4 + r;
            const int ch = wn*32 + ni*16 + li;
            const int head = grow >> 9, pos = grow & 511;
            vT[((size_t)head << 16) + ch*512 + pos] = f2bf(acc[mi][ni][r]);
          }
    }
  }
}

// ---------------- kernel 2: scores -> softmax -> w out; y = x + w.v ---------
__global__ __launch_bounds__(512,2) void k2_attn(const float* __restrict__ qk,
    const unsigned short* __restrict__ vT, const float* __restrict__ x,
    float* __restrict__ y, float* __restrict__ wout){
  __shared__ unsigned short qh[4096], ql[4096];   // 8 KB + 8 KB
  __shared__ unsigned short wlds[32768];          // 64 KB (swizzled bf16 w)
  __shared__ float redm[512], reds[512];          // cross-wave reductions

  const int t = threadIdx.x;
  const int lane = t & 63, wid = t >> 6;
  const int li = lane & 15, g = lane >> 4;
  const int bi = blockIdx.x;
  // XCD-grouped mapping: all 8 q-tiles of a head land on the same XCD
  const int head = (bi & 7) + 8*(bi >> 6);
  const int qt = (bi >> 3) & 7;
  const size_t hbase = (size_t)head * 512;
  const int q0 = qt * 64;

  // Phase A: stage q tile (64 rows x ch 0..63), split hi/lo, swizzled
  {
    const int row = t >> 3, c8 = (t & 7) * 8;
    const float* src = qk + (hbase + q0 + row)*128 + c8;
    const float4 v0 = ((const float4*)src)[0];
    const float4 v1 = ((const float4*)src)[1];
    const float vv[8] = {v0.x,v0.y,v0.z,v0.w,v1.x,v1.y,v1.z,v1.w};
    s16x8 h, l;
    #pragma unroll
    for (int j = 0; j < 8; ++j){
      const unsigned short hb = f2bf(vv[j]);
      h[j] = (short)hb;
      l[j] = (short)f2bf(vv[j] - bf2f(hb));
    }
    const int idx = swz64(row, c8);
    *(s16x8*)&qh[idx] = h;
    *(s16x8*)&ql[idx] = l;
  }
  __syncthreads();

  // Phase B: scores(64 x 512); wave owns k-slice [wid*64, +64)
  const int kbase = wid * 64;
  f32x4 acc[4][4] = {};
  #pragma unroll
  for (int ks = 0; ks < 2; ++ks){
    s16x8 kh[4], kl[4];
    #pragma unroll
    for (int ni = 0; ni < 4; ++ni){
      const float* kp = qk + (hbase + kbase + ni*16 + li)*128 + 64 + ks*32 + g*8;
      const float4 a = ((const float4*)kp)[0];
      const float4 b = ((const float4*)kp)[1];
      const float vv[8] = {a.x,a.y,a.z,a.w,b.x,b.y,b.z,b.w};
      #pragma unroll
      for (int j = 0; j < 8; ++j){
        const unsigned short hb = f2bf(vv[j]);
        kh[ni][j] = (short)hb;
        kl[ni][j] = (short)f2bf(vv[j] - bf2f(hb));
      }
    }
    const int col = ks*32 + g*8;
    s16x8 ah[4], al[4];
    #pragma unroll
    for (int mi = 0; mi < 4; ++mi){
      const int idx = swz64(mi*16 + li, col);
      ah[mi] = *(const s16x8*)&qh[idx];
      al[mi] = *(const s16x8*)&ql[idx];
    }
    #pragma unroll
    for (int mi = 0; mi < 4; ++mi)
      #pragma unroll
      for (int ni = 0; ni < 4; ++ni){
        acc[mi][ni] = MFMA_BF16(ah[mi], kh[ni], acc[mi][ni]);
        acc[mi][ni] = MFMA_BF16(ah[mi], kl[ni], acc[mi][ni]);
        acc[mi][ni] = MFMA_BF16(al[mi], kh[ni], acc[mi][ni]);
      }
  }

  // Phase C: exact softmax per row (in-wave shfl + cross-wave LDS)
  #pragma unroll
  for (int mi = 0; mi < 4; ++mi)
    #pragma unroll
    for (int r = 0; r < 4; ++r){
      float m = fmaxf(fmaxf(acc[mi][0][r], acc[mi][1][r]),
                      fmaxf(acc[mi][2][r], acc[mi][3][r]));
      #pragma unroll
      for (int d = 1; d < 16; d <<= 1) m = fmaxf(m, __shfl_xor(m, d));
      if (li == 0) redm[(mi*16 + g*4 + r)*8 + wid] = m;
    }
  __syncthreads();
  float inv[4][4];
  #pragma unroll
  for (int mi = 0; mi < 4; ++mi)
    #pragma unroll
    for (int r = 0; r < 4; ++r){
      const int row = mi*16 + g*4 + r;
      float m = redm[row*8];
      #pragma unroll
      for (int kk = 1; kk < 8; ++kk) m = fmaxf(m, redm[row*8 + kk]);
      float s = 0.f;
      #pragma unroll
      for (int ni = 0; ni < 4; ++ni){
        const float e = __expf(acc[mi][ni][r] - m);
        acc[mi][ni][r] = e;
        s += e;
      }
      #pragma unroll
      for (int d = 1; d < 16; d <<= 1) s += __shfl_xor(s, d);
      if (li == 0) reds[row*8 + wid] = s;
    }
  __syncthreads();
  #pragma unroll
  for (int mi = 0; mi < 4; ++mi)
    #pragma unroll
    for (int r = 0; r < 4; ++r){
      const int row = mi*16 + g*4 + r;
      float s = reds[row*8];
      #pragma unroll
      for (int kk = 1; kk < 8; ++kk) s += reds[row*8 + kk];
      inv[mi][r] = 1.0f / s;
    }

  // Phase D: write w (fp32) + stash bf16 copy in LDS for PV
  #pragma unroll
  for (int mi = 0; mi < 4; ++mi)
    #pragma unroll
    for (int ni = 0; ni < 4; ++ni)
      #pragma unroll
      for (int r = 0; r < 4; ++r){
        const int row = mi*16 + g*4 + r;
        const int col = kbase + ni*16 + li;
        const float wv = acc[mi][ni][r] * inv[mi][r];
        wout[(hbase + q0 + row)*512 + col] = wv;
        wlds[swz512(row, col)] = f2bf(wv);
      }
  __syncthreads();

  // Phase E: y-tile = w . v ; wave owns 16 output channels
  const int c0 = wid * 16;
  f32x4 yacc[4] = {};
  const unsigned short* vhead = vT + ((size_t)head << 16) + (size_t)(c0 + li)*512;
  #pragma unroll
  for (int kt = 0; kt < 16; ++kt){
    const int kp0 = kt*32 + g*8;
    const s16x8 vb = *(const s16x8*)&vhead[kp0];
    #pragma unroll
    for (int mi = 0; mi < 4; ++mi){
      const s16x8 aw = *(const s16x8*)&wlds[swz512(mi*16 + li, kp0)];
      yacc[mi] = MFMA_BF16(aw, vb, yacc[mi]);
    }
  }

  // epilogue: y = x + attn
  #pragma unroll
  for (int mi = 0; mi < 4; ++mi)
    #pragma unroll
    for (int r = 0; r < 4; ++r){
      const int row = mi*16 + g*4 + r;
      const size_t idx = (hbase + q0 + row)*128 + c0 + li;
      y[idx] = x[idx] + yacc[mi][r];
    }
}

extern "C" void kernel_launch(void* const* d_in, const int* in_sizes, int n_in,
                              void* d_out, int out_size, void* d_ws, size_t ws_size,
                              hipStream_t stream){
  (void)in_sizes; (void)n_in; (void)out_size; (void)ws_size;
  const float* x = (const float*)d_in[0];
  const float* W = (const float*)d_in[1];
  float* y    = (float*)d_out;                        // 33,554,432 f32
  float* wout = y + (size_t)33554432;                 // 134,217,728 f32

  char* ws = (char*)d_ws;
  float*          qk  = (float*)ws;                                   // 134,217,728 B
  unsigned short* vT  = (unsigned short*)(ws + 134217728ull);         //  67,108,864 B
  unsigned short* wtH = (unsigned short*)(ws + 201326592ull);         //      65,536 B
  unsigned short* wtL = (unsigned short*)(ws + 201392128ull);         //      65,536 B

  hipLaunchKernelGGL(k0_wt,   dim3(1),    dim3(256), 0, stream, W, wtH, wtL);
  hipLaunchKernelGGL(k1_qkv,  dim3(2048), dim3(512), 0, stream, x, wtH, wtL, qk, vT);
  hipLaunchKernelGGL(k2_attn, dim3(4096), dim3(512), 0, stream, qk, vT, x, y, wout);
}